// Round 10
// baseline (71.141 us; speedup 1.0000x reference)
//
#include <hip/hip_runtime.h>
#include <hip/hip_bf16.h>

#define NE 9
#define NDIM 1024
#define BM 128
#define BN 128
#define BK 64
#define KSPLIT 2
#define KHALF (NDIM / KSPLIT)    // 512
#define NTH (KHALF / BK)         // 8 K-steps per block
#define NSLOT_MAX 48             // sum ceil(cnt_e/128) <= 32+9=41; padded to 48
#define SPX (NSLOT_MAX / 8)      // 6 slots per XCD

typedef __attribute__((ext_vector_type(8))) short bf16x8;
typedef __attribute__((ext_vector_type(4))) float f32x4;

__device__ __forceinline__ unsigned pack2_bf16(float a, float b) {
    __hip_bfloat162 h = __float22bfloat162_rn(float2{a, b});
    return *reinterpret_cast<unsigned*>(&h);
}

__device__ __forceinline__ void gload_lds16(const void* g, void* l) {
    __builtin_amdgcn_global_load_lds(
        (const __attribute__((address_space(1))) unsigned int*)g,
        (__attribute__((address_space(3))) unsigned int*)l, 16, 0, 0);
}

// ------- fused prep: bucket + desc table (block 0) | W,x f32->bf16 (blocks 1+) -----
__global__ __launch_bounds__(256)
void prep_kernel(const float* __restrict__ x, const float* __restrict__ W,
                 const int* __restrict__ sidx,
                 unsigned short* __restrict__ xb, unsigned short* __restrict__ Wb,
                 int* __restrict__ perm, int4* __restrict__ desc, int nB) {
    if (blockIdx.x == 0) {
        __shared__ int cnt[NE];
        __shared__ int cur[NE];
        int t = threadIdx.x;
        if (t < NE) cnt[t] = 0;
        __syncthreads();
        for (int i = t; i < nB; i += 256) atomicAdd(&cnt[sidx[i]], 1);
        __syncthreads();
        if (t == 0) {
            int run = 0, s = 0;
            for (int e = 0; e < NE; ++e) {
                cur[e] = run;
                int c = cnt[e];
                for (int m0 = 0; m0 < c; m0 += BM) {
                    desc[s] = make_int4(e, run + m0, min(BM, c - m0), 0);
                    ++s;
                }
                run += c;
            }
            for (; s < NSLOT_MAX; ++s) desc[s] = make_int4(-1, 0, 1, 0);
        }
        __syncthreads();
        for (int i = t; i < nB; i += 256) {
            int p = atomicAdd(&cur[sidx[i]], 1);
            perm[p] = i;
        }
    } else {
        const int NW8 = NE * NDIM * (NDIM / 8);
        const int NX8 = nB * (NDIM / 8);
        const int tot = NW8 + NX8;
        const int stride = (gridDim.x - 1) * 256;
        for (int u = (blockIdx.x - 1) * 256 + threadIdx.x; u < tot; u += stride) {
            const float4* src;
            uint4* dst;
            if (u < NW8) {
                src = (const float4*)W + 2 * (size_t)u;
                dst = (uint4*)Wb + u;
            } else {
                size_t v = (size_t)(u - NW8);
                src = (const float4*)x + 2 * v;
                dst = (uint4*)xb + v;
            }
            float4 a = src[0], c = src[1];
            uint4 o;
            o.x = pack2_bf16(a.x, a.y);
            o.y = pack2_bf16(a.z, a.w);
            o.z = pack2_bf16(c.x, c.y);
            o.w = pack2_bf16(c.z, c.w);
            *dst = o;
        }
    }
}

// ------- init: out[i] = bias[sidx[i]] (full overwrite; exact base for atomics) ----
__global__ __launch_bounds__(256)
void bias_init_kernel(const float* __restrict__ bias, const int* __restrict__ sidx,
                      float* __restrict__ out, int nB) {
    const int tot = nB * (NDIM / 4);          // float4 units
    const int stride = gridDim.x * blockDim.x;
    for (int u = blockIdx.x * blockDim.x + threadIdx.x; u < tot; u += stride) {
        int row = u >> 8;                     // NDIM/4 = 256 units per row
        int c4 = u & 255;
        int e = sidx[row];
        ((float4*)out)[u] =
            ((const float4*)(bias + (size_t)e * NDIM))[c4];
    }
}

// ------- bf16 grouped GEMM, 2-way K-split: each block does K-half, atomicAdd out --
// 128x128 tile, 4 waves of 64x64, 64 KB LDS, 8 K-steps/block. Determinism: out
// starts at exact bias; exactly 2 commutative f32 adds per element.
__global__ __launch_bounds__(256, 2)
void gemm_kernel(const unsigned short* __restrict__ xb,
                 const unsigned short* __restrict__ Wb,
                 const int* __restrict__ perm,
                 const int4* __restrict__ desc,
                 float* __restrict__ out) {
    // XCD map: b&7 = XCD; each XCD owns SPX contiguous slots x 8 N x 2 Khalf
    const int b    = blockIdx.x;
    const int xcd  = b & 7;
    const int loc  = b >> 3;                 // 0..95
    const int slot = xcd * SPX + (loc >> 4);
    const int rem  = loc & 15;
    const int n    = rem >> 1;
    const int kh   = rem & 1;
    const int4 d   = desc[slot];
    if (d.x < 0) return;
    const int e = d.x, rowstart = d.y, rcnt = d.z;
    const int n0 = n * BN;
    const int k0base = kh * KHALF;

    // ushort idx: A bufs @ {0, 8192}, B bufs @ 16384 + {0, 8192}; 64 KB total
    __shared__ __align__(16) unsigned short lds[32768];

    const int t    = threadIdx.x;
    const int wave = t >> 6;
    const int lane = t & 63;
    const int fr   = lane & 15;
    const int fq   = lane >> 4;
    const int wr   = (wave >> 1) * 64;   // wave M-origin
    const int wc   = (wave & 1) * 64;    // wave N-origin
    const int xr   = fr & 7;             // read-side swizzle key

    // staging: 8 lanes per row; thread covers rows {i*32 + srow} i=0..3
    const int srow = t >> 3;                       // 0..31
    const int scol = ((t & 7) ^ (srow & 7)) * 8;   // pre-swizzled col (key = row&7)

    const unsigned short* asrc[4];
#pragma unroll
    for (int i = 0; i < 4; ++i) {
        int lm = i * 32 + srow;
        if (lm >= rcnt) lm = rcnt - 1;             // clamp; masked at store
        asrc[i] = xb + (size_t)perm[rowstart + lm] * NDIM + k0base + scol;
    }
    const unsigned short* bsrc =
        Wb + ((size_t)e * NDIM + n0 + srow) * NDIM + k0base + scol;

#define STAGE(BUF, K0)                                                         \
    do {                                                                       \
        _Pragma("unroll")                                                      \
        for (int i = 0; i < 4; ++i) {                                          \
            gload_lds16(asrc[i] + (K0),                                        \
                        &lds[(BUF) * 8192 + i * 2048 + wave * 512]);           \
            gload_lds16(bsrc + (size_t)i * 32 * NDIM + (K0),                   \
                        &lds[16384 + (BUF) * 8192 + i * 2048 + wave * 512]);   \
        }                                                                      \
    } while (0)

    f32x4 acc[4][4];
#pragma unroll
    for (int i = 0; i < 4; ++i)
#pragma unroll
        for (int k = 0; k < 4; ++k) acc[i][k] = (f32x4)(0.0f);

    STAGE(0, 0);
    __syncthreads();

    for (int tt = 0; tt < NTH; ++tt) {
        const int cur = tt & 1;
        if (tt + 1 < NTH) STAGE(cur ^ 1, (tt + 1) * BK);

        const int abase = cur * 8192;
        const int bbase = 16384 + cur * 8192;
#pragma unroll
        for (int kk = 0; kk < 2; ++kk) {
            const int cs = ((kk * 4 + fq) ^ xr) * 8;
            bf16x8 af[4], bfv[4];
#pragma unroll
            for (int mf = 0; mf < 4; ++mf)
                af[mf] = *reinterpret_cast<const bf16x8*>(
                    &lds[abase + (wr + mf * 16 + fr) * 64 + cs]);
#pragma unroll
            for (int nf = 0; nf < 4; ++nf)
                bfv[nf] = *reinterpret_cast<const bf16x8*>(
                    &lds[bbase + (wc + nf * 16 + fr) * 64 + cs]);
#pragma unroll
            for (int mf = 0; mf < 4; ++mf)
#pragma unroll
                for (int nf = 0; nf < 4; ++nf)
                    acc[mf][nf] = __builtin_amdgcn_mfma_f32_16x16x32_bf16(
                        af[mf], bfv[nf], acc[mf][nf], 0, 0, 0);
        }
        __syncthreads();
    }
#undef STAGE

    // ---- epilogue: atomic accumulate partial K-half into out (base = bias) ----
#pragma unroll
    for (int mf = 0; mf < 4; ++mf) {
#pragma unroll
        for (int jr = 0; jr < 4; ++jr) {
            int lm = wr + mf * 16 + fq * 4 + jr;
            if (lm < rcnt) {
                int grow = perm[rowstart + lm];
                float* orow = out + (size_t)grow * NDIM;
#pragma unroll
                for (int nf = 0; nf < 4; ++nf)
                    atomicAdd(&orow[n0 + wc + nf * 16 + fr], acc[mf][nf][jr]);
            }
        }
    }
}

// ---------------- tiny correct fallback (ws too small; not expected) --------------
__global__ void naive_kernel(const float* __restrict__ x, const float* __restrict__ W,
                             const float* __restrict__ bias,
                             const int* __restrict__ sidx, float* __restrict__ out,
                             int nB) {
    int i = blockIdx.x;
    int c = threadIdx.x + (blockIdx.y << 8);
    if (i >= nB || c >= NDIM) return;
    int e = sidx[i];
    const float* wrow = W + ((size_t)e * NDIM + c) * NDIM;
    const float* xr = x + (size_t)i * NDIM;
    float s = bias[e * NDIM + c];
    for (int k = 0; k < NDIM; ++k) s += xr[k] * wrow[k];
    out[(size_t)i * NDIM + c] = s;
}

extern "C" void kernel_launch(void* const* d_in, const int* in_sizes, int n_in,
                              void* d_out, int out_size, void* d_ws, size_t ws_size,
                              hipStream_t stream) {
    const float* x    = (const float*)d_in[0];
    const float* W    = (const float*)d_in[1];
    const float* bias = (const float*)d_in[2];
    const int*   sidx = (const int*)d_in[3];
    float*       out  = (float*)d_out;

    const int nB = in_sizes[3];   // 4096

    char* wsb = (char*)d_ws;
    size_t p_desc = (size_t)nB * 4;
    size_t p_xb   = ((p_desc + NSLOT_MAX * 16 + 511) / 512) * 512;
    size_t p_wb   = p_xb + (size_t)nB * NDIM * 2;
    size_t need   = p_wb + (size_t)NE * NDIM * NDIM * 2;

    if (ws_size < need) {
        dim3 g(nB, NDIM / 256);
        naive_kernel<<<g, 256, 0, stream>>>(x, W, bias, sidx, out, nB);
        return;
    }

    int*  perm = (int*)wsb;
    int4* desc = (int4*)(wsb + p_desc);
    unsigned short* xb = (unsigned short*)(wsb + p_xb);
    unsigned short* Wb = (unsigned short*)(wsb + p_wb);

    prep_kernel<<<1024, 256, 0, stream>>>(x, W, sidx, xb, Wb, perm, desc, nB);
    bias_init_kernel<<<2048, 256, 0, stream>>>(bias, sidx, out, nB);

    gemm_kernel<<<NSLOT_MAX * 16, 256, 0, stream>>>(xb, Wb, perm, desc, out);
}

// Round 11
// 59.490 us; speedup vs baseline: 1.1958x; 1.1958x over previous
//
#include <hip/hip_runtime.h>
#include <hip/hip_bf16.h>

#define NE 9
#define NDIM 1024
#define BM 64            // M-tile
#define BN 128           // N-tile
#define BK 64            // K-step
#define NT (NDIM / BK)   // 16
#define NSLOT_MAX 80     // sum ceil(cnt_e/64) <= 72; padded to 80 (10 per XCD)

typedef __attribute__((ext_vector_type(8))) short bf16x8;
typedef __attribute__((ext_vector_type(4))) float f32x4;

__device__ __forceinline__ unsigned pack2_bf16(float a, float b) {
    __hip_bfloat162 h = __float22bfloat162_rn(float2{a, b});
    return *reinterpret_cast<unsigned*>(&h);
}

__device__ __forceinline__ void gload_lds16(const void* g, void* l) {
    __builtin_amdgcn_global_load_lds(
        (const __attribute__((address_space(1))) unsigned int*)g,
        (__attribute__((address_space(3))) unsigned int*)l, 16, 0, 0);
}

// ------- prep: bucket + desc (block 0) | W f32->bf16 only (blocks 1+) -------------
// x is NOT converted here (GEMM converts A in-register) -> prep traffic 82->57 MB.
__global__ __launch_bounds__(256)
void prep_kernel(const float* __restrict__ W, const int* __restrict__ sidx,
                 unsigned short* __restrict__ Wb,
                 int* __restrict__ perm, int4* __restrict__ desc, int nB) {
    if (blockIdx.x == 0) {
        __shared__ int cnt[NE];
        __shared__ int cur[NE];
        int t = threadIdx.x;
        if (t < NE) cnt[t] = 0;
        __syncthreads();
        for (int i = t; i < nB; i += 256) atomicAdd(&cnt[sidx[i]], 1);
        __syncthreads();
        if (t == 0) {
            int run = 0, s = 0;
            for (int e = 0; e < NE; ++e) {
                cur[e] = run;
                int c = cnt[e];
                for (int m0 = 0; m0 < c; m0 += BM) {
                    desc[s] = make_int4(e, run + m0, min(BM, c - m0), 0);
                    ++s;
                }
                run += c;
            }
            for (; s < NSLOT_MAX; ++s) desc[s] = make_int4(-1, 0, 1, 0);
        }
        __syncthreads();
        for (int i = t; i < nB; i += 256) {
            int p = atomicAdd(&cur[sidx[i]], 1);
            perm[p] = i;
        }
    } else {
        const int NW8 = NE * NDIM * (NDIM / 8);
        const int stride = (gridDim.x - 1) * 256;
        for (int u = (blockIdx.x - 1) * 256 + threadIdx.x; u < NW8; u += stride) {
            const float4* src = (const float4*)W + 2 * (size_t)u;
            float4 a = src[0], c = src[1];
            uint4 o;
            o.x = pack2_bf16(a.x, a.y);
            o.y = pack2_bf16(a.z, a.w);
            o.z = pack2_bf16(c.x, c.y);
            o.w = pack2_bf16(c.z, c.w);
            ((uint4*)Wb)[u] = o;
        }
    }
}

// ------- grouped GEMM (R4 structure): A staged f32 from x, B bf16 from Wb ---------
// 256 thr = 4 waves (2M x 2N); wave tile 32x64. LDS 64 KB:
//   A f32 bufs @ bytes {0, 16384}  (64 rows x 64 f32, 16B-unit swizzle key (row&7)<<1)
//   B bf16 bufs @ bytes 32768 + {0, 16384}  (128 rows x 64 bf16, octet swizzle row&7)
__global__ __launch_bounds__(256, 2)
void gemm_kernel(const float* __restrict__ x,
                 const unsigned short* __restrict__ Wb,
                 const float* __restrict__ bias,
                 const int* __restrict__ perm,
                 const int4* __restrict__ desc,
                 float* __restrict__ out) {
    // static XCD map: XCD = b&7 owns 10 contiguous slots x 8 N-tiles
    const int b    = blockIdx.x;
    const int xcd  = b & 7;
    const int j    = b >> 3;               // 0..79
    const int slot = xcd * 10 + (j >> 3);
    const int n    = j & 7;
    const int4 d   = desc[slot];
    if (d.x < 0) return;
    const int e = d.x, rowstart = d.y, rcnt = d.z;
    const int n0 = n * BN;

    __shared__ __align__(16) unsigned char lds[65536];

    const int t    = threadIdx.x;
    const int wave = t >> 6;
    const int lane = t & 63;
    const int fr   = lane & 15;
    const int fq   = lane >> 4;
    const int wr   = (wave >> 1) * 32;   // wave M-origin (0 or 32)
    const int wc   = (wave & 1) * 64;    // wave N-origin (0 or 64)
    const int xrB  = fr & 7;             // B read swizzle key

    // ---- A staging map: 16 threads/row (16B units); rows i*16 + (t>>4) ----
    const int arl  = t >> 4;                         // row within 16-row group
    const int akey = (arl & 7) << 1;                 // swizzle key (even)
    const int aun  = (t & 15) ^ akey;                // pre-swizzled 16B unit
    const float* ap[4];
#pragma unroll
    for (int i = 0; i < 4; ++i) {
        int lm = i * 16 + arl;
        if (lm >= rcnt) lm = rcnt - 1;               // clamp; masked at store
        ap[i] = x + (size_t)perm[rowstart + lm] * NDIM + aun * 4;
    }
    // ---- B staging map: 8 threads/row (bf16 octets); rows i*32 + (t>>3) ----
    const int brl  = t >> 3;
    const unsigned short* bp =
        Wb + ((size_t)e * NDIM + n0 + brl) * NDIM + ((t & 7) ^ (brl & 7)) * 8;

#define STAGE(BUF, K0)                                                         \
    do {                                                                       \
        _Pragma("unroll")                                                      \
        for (int i = 0; i < 4; ++i)                                            \
            gload_lds16(ap[i] + (K0),                                          \
                        &lds[(BUF) * 16384 + i * 4096 + wave * 1024]);         \
        _Pragma("unroll")                                                      \
        for (int i = 0; i < 4; ++i)                                            \
            gload_lds16(bp + (size_t)i * 32 * NDIM + (K0),                     \
                        &lds[32768 + (BUF) * 16384 + i * 4096 + wave * 1024]); \
    } while (0)

    f32x4 acc[2][4];
#pragma unroll
    for (int i = 0; i < 2; ++i)
#pragma unroll
        for (int k = 0; k < 4; ++k) acc[i][k] = (f32x4)(0.0f);

    STAGE(0, 0);
    __syncthreads();

    for (int tt = 0; tt < NT; ++tt) {
        const int cur = tt & 1;
        if (tt + 1 < NT) STAGE(cur ^ 1, (tt + 1) * BK);

        const unsigned char* Ab = &lds[cur * 16384];
        const unsigned char* Bb = &lds[32768 + cur * 16384];
#pragma unroll
        for (int kk = 0; kk < 2; ++kk) {
            bf16x8 af[2], bfv[4];
#pragma unroll
            for (int mf = 0; mf < 2; ++mf) {
                const int row = wr + mf * 16 + fr;
                const int u   = (kk * 8 + fq * 2) ^ ((row & 7) << 1);
                const float4* pa =
                    reinterpret_cast<const float4*>(Ab + row * 256 + u * 16);
                float4 lo = pa[0], hi = pa[1];
                uint4 pk;
                pk.x = pack2_bf16(lo.x, lo.y);
                pk.y = pack2_bf16(lo.z, lo.w);
                pk.z = pack2_bf16(hi.x, hi.y);
                pk.w = pack2_bf16(hi.z, hi.w);
                af[mf] = *reinterpret_cast<bf16x8*>(&pk);
            }
#pragma unroll
            for (int nf = 0; nf < 4; ++nf) {
                const int row = wc + nf * 16 + fr;
                const int cs  = ((kk * 4 + fq) ^ xrB) * 8;
                bfv[nf] = *reinterpret_cast<const bf16x8*>(
                    Bb + row * 128 + cs * 2);
            }
#pragma unroll
            for (int mf = 0; mf < 2; ++mf)
#pragma unroll
                for (int nf = 0; nf < 4; ++nf)
                    acc[mf][nf] = __builtin_amdgcn_mfma_f32_16x16x32_bf16(
                        af[mf], bfv[nf], acc[mf][nf], 0, 0, 0);
        }
        __syncthreads();   // drains stage loads + protects buffer reuse
    }
#undef STAGE

    // ---- epilogue: bias add + scatter store via perm ----
    float bl[4];
#pragma unroll
    for (int nf = 0; nf < 4; ++nf)
        bl[nf] = bias[e * NDIM + n0 + wc + nf * 16 + fr];

#pragma unroll
    for (int mf = 0; mf < 2; ++mf) {
#pragma unroll
        for (int jr = 0; jr < 4; ++jr) {
            int lm = wr + mf * 16 + fq * 4 + jr;
            if (lm < rcnt) {
                int grow = perm[rowstart + lm];
                float* orow = out + (size_t)grow * NDIM;
#pragma unroll
                for (int nf = 0; nf < 4; ++nf)
                    orow[n0 + wc + nf * 16 + fr] = acc[mf][nf][jr] + bl[nf];
            }
        }
    }
}

// ---------------- tiny correct fallback (ws too small; not expected) --------------
__global__ void naive_kernel(const float* __restrict__ x, const float* __restrict__ W,
                             const float* __restrict__ bias,
                             const int* __restrict__ sidx, float* __restrict__ out,
                             int nB) {
    int i = blockIdx.x;
    int c = threadIdx.x + (blockIdx.y << 8);
    if (i >= nB || c >= NDIM) return;
    int e = sidx[i];
    const float* wrow = W + ((size_t)e * NDIM + c) * NDIM;
    const float* xr = x + (size_t)i * NDIM;
    float s = bias[e * NDIM + c];
    for (int k = 0; k < NDIM; ++k) s += xr[k] * wrow[k];
    out[(size_t)i * NDIM + c] = s;
}

extern "C" void kernel_launch(void* const* d_in, const int* in_sizes, int n_in,
                              void* d_out, int out_size, void* d_ws, size_t ws_size,
                              hipStream_t stream) {
    const float* x    = (const float*)d_in[0];
    const float* W    = (const float*)d_in[1];
    const float* bias = (const float*)d_in[2];
    const int*   sidx = (const int*)d_in[3];
    float*       out  = (float*)d_out;

    const int nB = in_sizes[3];   // 4096

    char* wsb = (char*)d_ws;
    size_t p_desc = (size_t)nB * 4;
    size_t p_wb   = ((p_desc + NSLOT_MAX * 16 + 511) / 512) * 512;
    size_t need   = p_wb + (size_t)NE * NDIM * NDIM * 2;

    if (ws_size < need) {
        dim3 g(nB, NDIM / 256);
        naive_kernel<<<g, 256, 0, stream>>>(x, W, bias, sidx, out, nB);
        return;
    }

    int*  perm = (int*)wsb;
    int4* desc = (int4*)(wsb + p_desc);
    unsigned short* Wb = (unsigned short*)(wsb + p_wb);

    prep_kernel<<<1024, 256, 0, stream>>>(W, sidx, Wb, perm, desc, nB);

    gemm_kernel<<<NSLOT_MAX * 8, 256, 0, stream>>>(x, Wb, bias, perm, desc, out);
}

// Round 12
// 51.968 us; speedup vs baseline: 1.3689x; 1.1447x over previous
//
#include <hip/hip_runtime.h>
#include <hip/hip_bf16.h>

#define NE 9
#define NDIM 1024
#define BM 128
#define BN 128
#define BK 128
#define NT (NDIM / BK)      // 8 K-steps
#define NSLOT_MAX 48        // sum ceil(cnt_e/128) <= 32+9=41; padded to 48
#define SPX (NSLOT_MAX / 8) // 6 slots per XCD

typedef __attribute__((ext_vector_type(8))) short bf16x8;
typedef __attribute__((ext_vector_type(4))) float f32x4;

__device__ __forceinline__ unsigned pack2_bf16(float a, float b) {
    __hip_bfloat162 h = __float22bfloat162_rn(float2{a, b});
    return *reinterpret_cast<unsigned*>(&h);
}

__device__ __forceinline__ void gload_lds16(const void* g, void* l) {
    __builtin_amdgcn_global_load_lds(
        (const __attribute__((address_space(1))) unsigned int*)g,
        (__attribute__((address_space(3))) unsigned int*)l, 16, 0, 0);
}

// ------- fused prep: bucket + desc table (block 0) | W,x f32->bf16 (blocks 1+) -----
__global__ __launch_bounds__(256)
void prep_kernel(const float* __restrict__ x, const float* __restrict__ W,
                 const int* __restrict__ sidx,
                 unsigned short* __restrict__ xb, unsigned short* __restrict__ Wb,
                 int* __restrict__ perm, int4* __restrict__ desc, int nB) {
    if (blockIdx.x == 0) {
        __shared__ int cnt[NE];
        __shared__ int cur[NE];
        int t = threadIdx.x;
        if (t < NE) cnt[t] = 0;
        __syncthreads();
        for (int i = t; i < nB; i += 256) atomicAdd(&cnt[sidx[i]], 1);
        __syncthreads();
        if (t == 0) {
            int run = 0, s = 0;
            for (int e = 0; e < NE; ++e) {
                cur[e] = run;
                int c = cnt[e];
                for (int m0 = 0; m0 < c; m0 += BM) {
                    desc[s] = make_int4(e, run + m0, min(BM, c - m0), 0);
                    ++s;
                }
                run += c;
            }
            for (; s < NSLOT_MAX; ++s) desc[s] = make_int4(-1, 0, 1, 0);
        }
        __syncthreads();
        for (int i = t; i < nB; i += 256) {
            int p = atomicAdd(&cur[sidx[i]], 1);
            perm[p] = i;
        }
    } else {
        const int NW8 = NE * NDIM * (NDIM / 8);
        const int NX8 = nB * (NDIM / 8);
        const int tot = NW8 + NX8;
        const int stride = (gridDim.x - 1) * 256;
        for (int u = (blockIdx.x - 1) * 256 + threadIdx.x; u < tot; u += stride) {
            const float4* src;
            uint4* dst;
            if (u < NW8) {
                src = (const float4*)W + 2 * (size_t)u;
                dst = (uint4*)Wb + u;
            } else {
                size_t v = (size_t)(u - NW8);
                src = (const float4*)x + 2 * v;
                dst = (uint4*)xb + v;
            }
            float4 a = src[0], c = src[1];
            uint4 o;
            o.x = pack2_bf16(a.x, a.y);
            o.y = pack2_bf16(a.z, a.w);
            o.z = pack2_bf16(c.x, c.y);
            o.w = pack2_bf16(c.z, c.w);
            *dst = o;
        }
    }
}

// ------- bf16 grouped GEMM: 128x128 tile, BK=128 (8 K-steps), 128 KB LDS ----------
// Halves the fixed per-step barrier/drain count vs BK=64 at identical staged bytes.
// 4 waves of 64x64; 64 MFMA per wave-step. 16B-unit XOR swizzle, key = row&7
// (full 8-bank-group spread; residual 2-way is free). 1 block/CU.
__global__ __launch_bounds__(256, 1)
void gemm_kernel(const unsigned short* __restrict__ xb,
                 const unsigned short* __restrict__ Wb,
                 const float* __restrict__ bias,
                 const int* __restrict__ perm,
                 const int4* __restrict__ desc,
                 float* __restrict__ out) {
    // bijective XCD map: XCD = b&7 owns SPX contiguous slots x 8 N-tiles
    const int b    = blockIdx.x;
    const int xcd  = b & 7;
    const int loc  = b >> 3;                 // 0..47
    const int slot = xcd * SPX + (loc >> 3);
    const int n    = loc & 7;
    const int4 d   = desc[slot];
    if (d.x < 0) return;
    const int e = d.x, rowstart = d.y, rcnt = d.z;
    const int n0 = n * BN;

    // byte layout: A0@0 A1@32K B0@64K B1@96K  (each 128 rows x 256 B)
    __shared__ __align__(16) unsigned char lds[131072];

    const int t    = threadIdx.x;
    const int wave = t >> 6;
    const int lane = t & 63;
    const int fr   = lane & 15;
    const int fq   = lane >> 4;
    const int wr   = (wave >> 1) * 64;   // wave M-origin
    const int wc   = (wave & 1) * 64;    // wave N-origin
    const int xr   = fr & 7;             // read swizzle key (= row&7 for all frags)

    // staging: 16 threads/row (16B units, 16 per row); instr i covers rows i*16+srw.
    // key (row&7) == (srw&7) since i*16 = 0 mod 8 -> pre-swizzled unit is constant.
    const int srw = t >> 4;                        // 0..15
    const int sun = (t & 15) ^ (srw & 7);          // pre-swizzled 16B unit

    const unsigned short* ap[8];
#pragma unroll
    for (int i = 0; i < 8; ++i) {
        int lm = i * 16 + srw;
        if (lm >= rcnt) lm = rcnt - 1;             // clamp; masked at store
        ap[i] = xb + (size_t)perm[rowstart + lm] * NDIM + sun * 8;
    }
    const unsigned short* bp =
        Wb + ((size_t)e * NDIM + n0 + srw) * NDIM + sun * 8;

#define STAGE(BUF, K0)                                                         \
    do {                                                                       \
        _Pragma("unroll")                                                      \
        for (int i = 0; i < 8; ++i)                                            \
            gload_lds16(ap[i] + (K0),                                          \
                        &lds[(BUF) * 32768 + i * 4096 + wave * 1024]);         \
        _Pragma("unroll")                                                      \
        for (int i = 0; i < 8; ++i)                                            \
            gload_lds16(bp + (size_t)i * 16 * NDIM + (K0),                     \
                        &lds[65536 + (BUF) * 32768 + i * 4096 + wave * 1024]); \
    } while (0)

    f32x4 acc[4][4];
#pragma unroll
    for (int i = 0; i < 4; ++i)
#pragma unroll
        for (int k = 0; k < 4; ++k) acc[i][k] = (f32x4)(0.0f);

    STAGE(0, 0);
    __syncthreads();

    for (int tt = 0; tt < NT; ++tt) {
        const int cur = tt & 1;
        // issue next tile's DMA first; it flies under this tile's compute
        if (tt + 1 < NT) STAGE(cur ^ 1, (tt + 1) * BK);

        const unsigned char* Ab = &lds[cur * 32768];
        const unsigned char* Bb = &lds[65536 + cur * 32768];
#pragma unroll
        for (int kk = 0; kk < 4; ++kk) {
            const int slotk = (kk * 4 + fq) ^ xr;   // 16B-unit slot, same A and B
            bf16x8 af[4], bfv[4];
#pragma unroll
            for (int mf = 0; mf < 4; ++mf)
                af[mf] = *reinterpret_cast<const bf16x8*>(
                    Ab + (wr + mf * 16 + fr) * 256 + slotk * 16);
#pragma unroll
            for (int nf = 0; nf < 4; ++nf)
                bfv[nf] = *reinterpret_cast<const bf16x8*>(
                    Bb + (wc + nf * 16 + fr) * 256 + slotk * 16);
#pragma unroll
            for (int mf = 0; mf < 4; ++mf)
#pragma unroll
                for (int nf = 0; nf < 4; ++nf)
                    acc[mf][nf] = __builtin_amdgcn_mfma_f32_16x16x32_bf16(
                        af[mf], bfv[nf], acc[mf][nf], 0, 0, 0);
        }
        __syncthreads();   // drains stage loads + protects buffer reuse
    }
#undef STAGE

    // ---- epilogue: bias add + scatter store via perm ----
    float bl[4];
#pragma unroll
    for (int nf = 0; nf < 4; ++nf)
        bl[nf] = bias[e * NDIM + n0 + wc + nf * 16 + fr];

#pragma unroll
    for (int mf = 0; mf < 4; ++mf) {
#pragma unroll
        for (int jr = 0; jr < 4; ++jr) {
            int lm = wr + mf * 16 + fq * 4 + jr;
            if (lm < rcnt) {
                int grow = perm[rowstart + lm];
                float* orow = out + (size_t)grow * NDIM;
#pragma unroll
                for (int nf = 0; nf < 4; ++nf)
                    orow[n0 + wc + nf * 16 + fr] = acc[mf][nf][jr] + bl[nf];
            }
        }
    }
}

// ---------------- tiny correct fallback (ws too small; not expected) --------------
__global__ void naive_kernel(const float* __restrict__ x, const float* __restrict__ W,
                             const float* __restrict__ bias,
                             const int* __restrict__ sidx, float* __restrict__ out,
                             int nB) {
    int i = blockIdx.x;
    int c = threadIdx.x + (blockIdx.y << 8);
    if (i >= nB || c >= NDIM) return;
    int e = sidx[i];
    const float* wrow = W + ((size_t)e * NDIM + c) * NDIM;
    const float* xr = x + (size_t)i * NDIM;
    float s = bias[e * NDIM + c];
    for (int k = 0; k < NDIM; ++k) s += xr[k] * wrow[k];
    out[(size_t)i * NDIM + c] = s;
}

extern "C" void kernel_launch(void* const* d_in, const int* in_sizes, int n_in,
                              void* d_out, int out_size, void* d_ws, size_t ws_size,
                              hipStream_t stream) {
    const float* x    = (const float*)d_in[0];
    const float* W    = (const float*)d_in[1];
    const float* bias = (const float*)d_in[2];
    const int*   sidx = (const int*)d_in[3];
    float*       out  = (float*)d_out;

    const int nB = in_sizes[3];   // 4096

    char* wsb = (char*)d_ws;
    size_t p_desc = (size_t)nB * 4;
    size_t p_xb   = ((p_desc + NSLOT_MAX * 16 + 511) / 512) * 512;
    size_t p_wb   = p_xb + (size_t)nB * NDIM * 2;
    size_t need   = p_wb + (size_t)NE * NDIM * NDIM * 2;

    if (ws_size < need) {
        dim3 g(nB, NDIM / 256);
        naive_kernel<<<g, 256, 0, stream>>>(x, W, bias, sidx, out, nB);
        return;
    }

    int*  perm = (int*)wsb;
    int4* desc = (int4*)(wsb + p_desc);
    unsigned short* xb = (unsigned short*)(wsb + p_xb);
    unsigned short* Wb = (unsigned short*)(wsb + p_wb);

    prep_kernel<<<1024, 256, 0, stream>>>(x, W, sidx, xb, Wb, perm, desc, nB);

    gemm_kernel<<<NSLOT_MAX * 8, 256, 0, stream>>>(xb, Wb, bias, perm, desc, out);
}